// Round 1
// baseline (1367.538 us; speedup 1.0000x reference)
//
#include <hip/hip_runtime.h>

#define NN 50000
#define NE 640000
#define IC 128
#define HC 256
#define OC 3
#define NT 16   // nodes per block in gemm0

// ---------------- kernel 1: deg + scatter x[src] into agg0[dst] ----------------
// thread = (edge, quad-of-4-channels). 82M float atomics total, targets stay in L2/L3.
__global__ __launch_bounds__(256) void k_scatter0(const float* __restrict__ x,
                                                  const int* __restrict__ ei,
                                                  float* __restrict__ agg0,
                                                  float* __restrict__ deg) {
    int idx = blockIdx.x * blockDim.x + threadIdx.x;
    if (idx >= NE * 32) return;
    int e = idx >> 5;          // edge
    int q = idx & 31;          // which float4 of the 128-ch row
    int src = ei[e];
    int dst = ei[NE + e];
    float4 xv = ((const float4*)x)[src * 32 + q];
    float* a = agg0 + (size_t)dst * IC + q * 4;
    unsafeAtomicAdd(a + 0, xv.x);
    unsafeAtomicAdd(a + 1, xv.y);
    unsafeAtomicAdd(a + 2, xv.z);
    unsafeAtomicAdd(a + 3, xv.w);
    if (q == 0) unsafeAtomicAdd(&deg[dst], 1.0f);   // integer-valued => exact/deterministic
}

// ---------------- kernel 2: h = relu([mean0 | x] @ [Wl0;Wr0] + bl0) ----------------
// block = 256 threads (one output column each), NT=16 nodes staged in LDS transposed [k][n].
__global__ __launch_bounds__(256) void k_gemm0(const float* __restrict__ x,
                                               const float* __restrict__ agg0,
                                               const float* __restrict__ deg,
                                               const float* __restrict__ Wl0,
                                               const float* __restrict__ bl0,
                                               const float* __restrict__ Wr0,
                                               float* __restrict__ h) {
    __shared__ float in_s[2 * IC][20];   // [k][n], padded 16->20 to spread banks; rows 16B-aligned
    __shared__ float invd[NT];
    int t = threadIdx.x;
    int n0 = blockIdx.x * NT;

    if (t < NT) {
        float d = deg[n0 + t];
        invd[t] = 1.0f / fmaxf(d, 1.0f);
    }
    __syncthreads();

    #pragma unroll
    for (int it = 0; it < NT; ++it) {
        int node = n0 + it;
        float v;
        if (t < IC) v = agg0[(size_t)node * IC + t] * invd[it];
        else        v = x[(size_t)node * IC + (t - IC)];
        in_s[t][it] = v;
    }
    __syncthreads();

    float acc[NT];
    #pragma unroll
    for (int n = 0; n < NT; ++n) acc[n] = 0.0f;

    for (int k = 0; k < IC; ++k) {
        float wl = Wl0[k * HC + t];
        float wr = Wr0[k * HC + t];
        #pragma unroll
        for (int n = 0; n < NT; ++n) {
            acc[n] = fmaf(in_s[k][n], wl, acc[n]);
            acc[n] = fmaf(in_s[IC + k][n], wr, acc[n]);
        }
    }

    float b = bl0[t];
    #pragma unroll
    for (int n = 0; n < NT; ++n) {
        float v = acc[n] + b;
        h[(size_t)(n0 + n) * HC + t] = fmaxf(v, 0.0f);
    }
}

// ---------------- kernel 3: g = h @ Wl1, r = h @ Wr1 (both 256->3) ----------------
// one wave per node; weights staged transposed in LDS, float4 reads, shuffle reduce.
__global__ __launch_bounds__(256) void k_gemm1(const float* __restrict__ h,
                                               const float* __restrict__ Wl1,
                                               const float* __restrict__ Wr1,
                                               float* __restrict__ g,
                                               float* __restrict__ r) {
    __shared__ float wt[2][OC][HC];
    for (int i = threadIdx.x; i < OC * HC; i += 256) {
        int j = i / HC, k = i % HC;
        wt[0][j][k] = Wl1[k * OC + j];
        wt[1][j][k] = Wr1[k * OC + j];
    }
    __syncthreads();

    int wid = (blockIdx.x * blockDim.x + threadIdx.x) >> 6;
    int lane = threadIdx.x & 63;
    if (wid >= NN) return;

    float4 hv = ((const float4*)h)[(size_t)wid * 64 + lane];
    float a[6];
    #pragma unroll
    for (int m = 0; m < 2; ++m) {
        #pragma unroll
        for (int j = 0; j < OC; ++j) {
            float4 wv = ((const float4*)&wt[m][j][0])[lane];
            a[m * 3 + j] = hv.x * wv.x + hv.y * wv.y + hv.z * wv.z + hv.w * wv.w;
        }
    }
    #pragma unroll
    for (int q = 0; q < 6; ++q) {
        #pragma unroll
        for (int off = 32; off > 0; off >>= 1)
            a[q] += __shfl_down(a[q], off);
    }
    if (lane == 0) {
        g[wid * 3 + 0] = a[0]; g[wid * 3 + 1] = a[1]; g[wid * 3 + 2] = a[2];
        r[wid * 3 + 0] = a[3]; r[wid * 3 + 1] = a[4]; r[wid * 3 + 2] = a[5];
    }
}

// ---------------- kernel 4: s1[dst] += g[src]  (3 floats per edge) ----------------
__global__ __launch_bounds__(256) void k_scatter1(const int* __restrict__ ei,
                                                  const float* __restrict__ g,
                                                  float* __restrict__ s1) {
    int e = blockIdx.x * blockDim.x + threadIdx.x;
    if (e >= NE) return;
    int src = ei[e];
    int dst = ei[NE + e];
    unsafeAtomicAdd(&s1[dst * 3 + 0], g[src * 3 + 0]);
    unsafeAtomicAdd(&s1[dst * 3 + 1], g[src * 3 + 1]);
    unsafeAtomicAdd(&s1[dst * 3 + 2], g[src * 3 + 2]);
}

// ---------------- kernel 5: out = s1/deg + bl1 + r ----------------
__global__ __launch_bounds__(256) void k_final(const float* __restrict__ s1,
                                               const float* __restrict__ deg,
                                               const float* __restrict__ r,
                                               const float* __restrict__ bl1,
                                               float* __restrict__ out) {
    int i = blockIdx.x * blockDim.x + threadIdx.x;
    if (i >= NN * OC) return;
    int n = i / OC;
    int j = i - n * OC;
    float d = fmaxf(deg[n], 1.0f);
    out[i] = s1[i] / d + bl1[j] + r[i];
}

extern "C" void kernel_launch(void* const* d_in, const int* in_sizes, int n_in,
                              void* d_out, int out_size, void* d_ws, size_t ws_size,
                              hipStream_t stream) {
    const float* x   = (const float*)d_in[0];
    const int*   ei  = (const int*)d_in[1];
    const float* Wl0 = (const float*)d_in[2];
    const float* bl0 = (const float*)d_in[3];
    const float* Wr0 = (const float*)d_in[4];
    const float* Wl1 = (const float*)d_in[5];
    const float* bl1 = (const float*)d_in[6];
    const float* Wr1 = (const float*)d_in[7];
    float* out = (float*)d_out;

    char* ws = (char*)d_ws;
    // layout (bytes):
    float* agg0 = (float*)(ws);                       // 25,600,000  (NN*IC*4)
    float* deg  = (float*)(ws + 25600000);            //    200,000  (NN*4)
    float* s1   = (float*)(ws + 25800000);            //    600,000  (NN*3*4)
    float* h    = (float*)(ws + 26400000);            // 51,200,000  (NN*HC*4)
    float* g    = (float*)(ws + 77600000);            //    600,000
    float* r    = (float*)(ws + 78200000);            //    600,000  -> total 78.8 MB

    // zero the accumulation buffers (agg0, deg, s1 are contiguous at ws start)
    hipMemsetAsync(ws, 0, 26400000, stream);

    k_scatter0<<<(NE * 32) / 256, 256, 0, stream>>>(x, ei, agg0, deg);
    k_gemm0<<<NN / NT, 256, 0, stream>>>(x, agg0, deg, Wl0, bl0, Wr0, h);
    k_gemm1<<<(NN * 64) / 256, 256, 0, stream>>>(h, Wl1, Wr1, g, r);
    k_scatter1<<<(NE + 255) / 256, 256, 0, stream>>>(ei, g, s1);
    k_final<<<(NN * OC + 255) / 256, 256, 0, stream>>>(s1, deg, r, bl1, out);
}

// Round 2
// 447.916 us; speedup vs baseline: 3.0531x; 3.0531x over previous
//
#include <hip/hip_runtime.h>

#define NN 50000
#define NE 640000
#define IC 128
#define HC 256
#define OC 3
#define NT 16   // nodes per block in gemm0

// ---------------- kernel 1: per-dst degree + per-edge rank ----------------
__global__ __launch_bounds__(256) void k_deg(const int* __restrict__ ei,
                                             int* __restrict__ degi,
                                             int* __restrict__ pos) {
    int e = blockIdx.x * blockDim.x + threadIdx.x;
    if (e >= NE) return;
    int dst = ei[NE + e];
    pos[e] = atomicAdd(&degi[dst], 1);
}

// ---------------- kernel 2: single-block exclusive scan of degi -> rowstart ----------------
__global__ __launch_bounds__(1024) void k_scan(const int* __restrict__ degi,
                                               int* __restrict__ rowstart) {
    __shared__ int sums[1024];
    int t = threadIdx.x;
    const int CH = (NN + 1023) / 1024;   // 49 elements per thread
    int base = t * CH;
    int s = 0;
    for (int i = 0; i < CH; ++i) {
        int idx = base + i;
        if (idx < NN) s += degi[idx];
    }
    sums[t] = s;
    __syncthreads();
    // Hillis-Steele inclusive scan over the 1024 partial sums
    for (int off = 1; off < 1024; off <<= 1) {
        int v = (t >= off) ? sums[t - off] : 0;
        __syncthreads();
        sums[t] += v;
        __syncthreads();
    }
    int excl = (t == 0) ? 0 : sums[t - 1];
    for (int i = 0; i < CH; ++i) {
        int idx = base + i;
        if (idx < NN) {
            rowstart[idx] = excl;
            excl += degi[idx];
        }
    }
    if (t == 1023) rowstart[NN] = NE;
}

// ---------------- kernel 3: fill CSR edge array ----------------
__global__ __launch_bounds__(256) void k_fill(const int* __restrict__ ei,
                                              const int* __restrict__ rowstart,
                                              const int* __restrict__ pos,
                                              int* __restrict__ csr) {
    int e = blockIdx.x * blockDim.x + threadIdx.x;
    if (e >= NE) return;
    int src = ei[e];
    int dst = ei[NE + e];
    csr[rowstart[dst] + pos[e]] = src;
}

// ---------------- kernel 4: gather-mean aggregation (wave per node) ----------------
__global__ __launch_bounds__(256) void k_agg(const float* __restrict__ x,
                                             const int* __restrict__ rowstart,
                                             const int* __restrict__ csr,
                                             float* __restrict__ agg0) {
    int wid = (blockIdx.x * blockDim.x + threadIdx.x) >> 6;
    int lane = threadIdx.x & 63;
    if (wid >= NN) return;
    int beg = rowstart[wid], end = rowstart[wid + 1];
    float ax = 0.0f, ay = 0.0f;
    for (int j = beg; j < end; ++j) {
        int src = csr[j];                                  // uniform across wave
        float2 v = ((const float2*)x)[(size_t)src * 64 + lane];
        ax += v.x; ay += v.y;
    }
    float inv = 1.0f / fmaxf((float)(end - beg), 1.0f);
    ((float2*)agg0)[(size_t)wid * 64 + lane] = make_float2(ax * inv, ay * inv);
}

// ---------------- kernel 5: h = relu([mean0 | x] @ [Wl0;Wr0] + bl0) ----------------
__global__ __launch_bounds__(256) void k_gemm0(const float* __restrict__ x,
                                               const float* __restrict__ agg0,
                                               const float* __restrict__ Wl0,
                                               const float* __restrict__ bl0,
                                               const float* __restrict__ Wr0,
                                               float* __restrict__ h) {
    __shared__ float in_s[2 * IC][20];   // [k][n], padded to spread banks
    int t = threadIdx.x;
    int n0 = blockIdx.x * NT;

    #pragma unroll
    for (int it = 0; it < NT; ++it) {
        int node = n0 + it;
        float v;
        if (t < IC) v = agg0[(size_t)node * IC + t];
        else        v = x[(size_t)node * IC + (t - IC)];
        in_s[t][it] = v;
    }
    __syncthreads();

    float acc[NT];
    #pragma unroll
    for (int n = 0; n < NT; ++n) acc[n] = 0.0f;

    for (int k = 0; k < IC; ++k) {
        float wl = Wl0[k * HC + t];
        float wr = Wr0[k * HC + t];
        #pragma unroll
        for (int n = 0; n < NT; ++n) {
            acc[n] = fmaf(in_s[k][n], wl, acc[n]);
            acc[n] = fmaf(in_s[IC + k][n], wr, acc[n]);
        }
    }

    float b = bl0[t];
    #pragma unroll
    for (int n = 0; n < NT; ++n) {
        float v = acc[n] + b;
        h[(size_t)(n0 + n) * HC + t] = fmaxf(v, 0.0f);
    }
}

// ---------------- kernel 6: g = h @ Wl1, r = h @ Wr1 (256->3 each) ----------------
__global__ __launch_bounds__(256) void k_gemm1(const float* __restrict__ h,
                                               const float* __restrict__ Wl1,
                                               const float* __restrict__ Wr1,
                                               float* __restrict__ g,
                                               float* __restrict__ r) {
    __shared__ float wt[2][OC][HC];
    for (int i = threadIdx.x; i < OC * HC; i += 256) {
        int j = i / HC, k = i % HC;
        wt[0][j][k] = Wl1[k * OC + j];
        wt[1][j][k] = Wr1[k * OC + j];
    }
    __syncthreads();

    int wid = (blockIdx.x * blockDim.x + threadIdx.x) >> 6;
    int lane = threadIdx.x & 63;
    if (wid >= NN) return;

    float4 hv = ((const float4*)h)[(size_t)wid * 64 + lane];
    float a[6];
    #pragma unroll
    for (int m = 0; m < 2; ++m) {
        #pragma unroll
        for (int j = 0; j < OC; ++j) {
            float4 wv = ((const float4*)&wt[m][j][0])[lane];
            a[m * 3 + j] = hv.x * wv.x + hv.y * wv.y + hv.z * wv.z + hv.w * wv.w;
        }
    }
    #pragma unroll
    for (int q = 0; q < 6; ++q) {
        #pragma unroll
        for (int off = 32; off > 0; off >>= 1)
            a[q] += __shfl_down(a[q], off);
    }
    if (lane == 0) {
        g[wid * 3 + 0] = a[0]; g[wid * 3 + 1] = a[1]; g[wid * 3 + 2] = a[2];
        r[wid * 3 + 0] = a[3]; r[wid * 3 + 1] = a[4]; r[wid * 3 + 2] = a[5];
    }
}

// ---------------- kernel 7: s1[dst] += g[src] (3 floats/edge, 1.9M atomics) ----------------
__global__ __launch_bounds__(256) void k_scatter1(const int* __restrict__ ei,
                                                  const float* __restrict__ g,
                                                  float* __restrict__ s1) {
    int e = blockIdx.x * blockDim.x + threadIdx.x;
    if (e >= NE) return;
    int src = ei[e];
    int dst = ei[NE + e];
    unsafeAtomicAdd(&s1[dst * 3 + 0], g[src * 3 + 0]);
    unsafeAtomicAdd(&s1[dst * 3 + 1], g[src * 3 + 1]);
    unsafeAtomicAdd(&s1[dst * 3 + 2], g[src * 3 + 2]);
}

// ---------------- kernel 8: out = s1/deg + bl1 + r ----------------
__global__ __launch_bounds__(256) void k_final(const float* __restrict__ s1,
                                               const int* __restrict__ degi,
                                               const float* __restrict__ r,
                                               const float* __restrict__ bl1,
                                               float* __restrict__ out) {
    int i = blockIdx.x * blockDim.x + threadIdx.x;
    if (i >= NN * OC) return;
    int n = i / OC;
    int j = i - n * OC;
    float d = fmaxf((float)degi[n], 1.0f);
    out[i] = s1[i] / d + bl1[j] + r[i];
}

extern "C" void kernel_launch(void* const* d_in, const int* in_sizes, int n_in,
                              void* d_out, int out_size, void* d_ws, size_t ws_size,
                              hipStream_t stream) {
    const float* x   = (const float*)d_in[0];
    const int*   ei  = (const int*)d_in[1];
    const float* Wl0 = (const float*)d_in[2];
    const float* bl0 = (const float*)d_in[3];
    const float* Wr0 = (const float*)d_in[4];
    const float* Wl1 = (const float*)d_in[5];
    const float* bl1 = (const float*)d_in[6];
    const float* Wr1 = (const float*)d_in[7];
    float* out = (float*)d_out;

    char* ws = (char*)d_ws;
    // layout (bytes), all 64B-aligned:
    int*   degi     = (int*)(ws);                        //    200,064 (NN, pad)
    float* s1       = (float*)(ws + 200064);             //    600,064 (NN*3, pad)
    int*   pos      = (int*)(ws + 800128);               //  2,560,000 (NE)
    int*   rowstart = (int*)(ws + 3360128);              //    200,064 (NN+1, pad)
    int*   csr      = (int*)(ws + 3560192);              //  2,560,000 (NE)
    float* agg0     = (float*)(ws + 6120192);            // 25,600,000 (NN*IC)
    float* h        = (float*)(ws + 31720192);           // 51,200,000 (NN*HC)
    float* g        = (float*)(ws + 82920192);           //    600,064
    float* r        = (float*)(ws + 83520256);           //    600,064  -> ~84.1 MB

    // zero only the accumulated buffers: degi + s1 (contiguous at ws start)
    hipMemsetAsync(ws, 0, 800128, stream);

    k_deg    <<<(NE + 255) / 256, 256, 0, stream>>>(ei, degi, pos);
    k_scan   <<<1, 1024, 0, stream>>>(degi, rowstart);
    k_fill   <<<(NE + 255) / 256, 256, 0, stream>>>(ei, rowstart, pos, csr);
    k_agg    <<<(NN * 64 + 255) / 256, 256, 0, stream>>>(x, rowstart, csr, agg0);
    k_gemm0  <<<NN / NT, 256, 0, stream>>>(x, agg0, Wl0, bl0, Wr0, h);
    k_gemm1  <<<(NN * 64 + 255) / 256, 256, 0, stream>>>(h, Wl1, Wr1, g, r);
    k_scatter1<<<(NE + 255) / 256, 256, 0, stream>>>(ei, g, s1);
    k_final  <<<(NN * OC + 255) / 256, 256, 0, stream>>>(s1, degi, r, bl1, out);
}

// Round 3
// 419.048 us; speedup vs baseline: 3.2634x; 1.0689x over previous
//
#include <hip/hip_runtime.h>

#define NN 50000
#define NE 640000
#define IC 128
#define HC 256
#define OC 3
#define NT0 48   // nodes per block in fused gemm0

// ---------------- kernel 1: per-dst degree + per-edge rank ----------------
__global__ __launch_bounds__(256) void k_deg(const int* __restrict__ ei,
                                             int* __restrict__ degi,
                                             int* __restrict__ pos) {
    int e = blockIdx.x * blockDim.x + threadIdx.x;
    if (e >= NE) return;
    int dst = ei[NE + e];
    pos[e] = atomicAdd(&degi[dst], 1);
}

// ---------------- kernel 2: single-block exclusive scan of degi -> rowstart ----------------
__global__ __launch_bounds__(1024) void k_scan(const int* __restrict__ degi,
                                               int* __restrict__ rowstart) {
    __shared__ int sums[1024];
    int t = threadIdx.x;
    const int CH = (NN + 1023) / 1024;
    int base = t * CH;
    int s = 0;
    for (int i = 0; i < CH; ++i) {
        int idx = base + i;
        if (idx < NN) s += degi[idx];
    }
    sums[t] = s;
    __syncthreads();
    for (int off = 1; off < 1024; off <<= 1) {
        int v = (t >= off) ? sums[t - off] : 0;
        __syncthreads();
        sums[t] += v;
        __syncthreads();
    }
    int excl = (t == 0) ? 0 : sums[t - 1];
    for (int i = 0; i < CH; ++i) {
        int idx = base + i;
        if (idx < NN) {
            rowstart[idx] = excl;
            excl += degi[idx];
        }
    }
    if (t == 1023) rowstart[NN] = NE;
}

// ---------------- kernel 3: fill CSR edge array ----------------
__global__ __launch_bounds__(256) void k_fill(const int* __restrict__ ei,
                                              const int* __restrict__ rowstart,
                                              const int* __restrict__ pos,
                                              int* __restrict__ csr) {
    int e = blockIdx.x * blockDim.x + threadIdx.x;
    if (e >= NE) return;
    int src = ei[e];
    int dst = ei[NE + e];
    csr[rowstart[dst] + pos[e]] = src;
}

// ---------------- kernel 4: gather-mean aggregation (wave per node) ----------------
__global__ __launch_bounds__(256) void k_agg(const float* __restrict__ x,
                                             const int* __restrict__ rowstart,
                                             const int* __restrict__ csr,
                                             float* __restrict__ agg0) {
    int wid = (blockIdx.x * blockDim.x + threadIdx.x) >> 6;
    int lane = threadIdx.x & 63;
    if (wid >= NN) return;
    int beg = rowstart[wid], end = rowstart[wid + 1];
    float ax = 0.0f, ay = 0.0f;
    for (int j = beg; j < end; ++j) {
        int src = csr[j];
        float2 v = ((const float2*)x)[(size_t)src * 64 + lane];
        ax += v.x; ay += v.y;
    }
    float inv = 1.0f / fmaxf((float)(end - beg), 1.0f);
    ((float2*)agg0)[(size_t)wid * 64 + lane] = make_float2(ax * inv, ay * inv);
}

// ---------------- kernel 5: fused h=relu([mean|x]@[Wl0;Wr0]+bl0); g=h@Wl1; r=h@Wr1 ----------------
__device__ __forceinline__ void fma4(float4& a, float s, const float4& w) {
    a.x = fmaf(s, w.x, a.x); a.y = fmaf(s, w.y, a.y);
    a.z = fmaf(s, w.z, a.z); a.w = fmaf(s, w.w, a.w);
}

__global__ __launch_bounds__(256, 3) void k_gemm0f(const float* __restrict__ x,
                                                   const float* __restrict__ agg0,
                                                   const float* __restrict__ Wl0,
                                                   const float* __restrict__ bl0,
                                                   const float* __restrict__ Wr0,
                                                   const float* __restrict__ Wl1,
                                                   const float* __restrict__ Wr1,
                                                   float* __restrict__ g,
                                                   float* __restrict__ r) {
    __shared__ float in_s[2 * IC][NT0];   // [k][n], 48 KB -> 3 blocks/CU
    int t = threadIdx.x;
    int nbase = blockIdx.x * NT0;

    // stage: thread t supplies k=t for all 48 nodes, 4 at a time (coalesced global, b128 LDS write)
    const float* srcp = (t < IC) ? (agg0 + t) : (x + (t - IC));
    #pragma unroll
    for (int j = 0; j < NT0 / 4; ++j) {
        int n0 = nbase + j * 4;
        float4 v;
        v.x = (n0 + 0 < NN) ? srcp[(size_t)(n0 + 0) * IC] : 0.0f;
        v.y = (n0 + 1 < NN) ? srcp[(size_t)(n0 + 1) * IC] : 0.0f;
        v.z = (n0 + 2 < NN) ? srcp[(size_t)(n0 + 2) * IC] : 0.0f;
        v.w = (n0 + 3 < NN) ? srcp[(size_t)(n0 + 3) * IC] : 0.0f;
        *(float4*)&in_s[t][j * 4] = v;
    }
    __syncthreads();

    int c4 = t & 63;        // this thread's float4-column index (cols c4*4 .. c4*4+3)
    int ng = t >> 6;        // wave id: owns nodes ng*12 .. ng*12+11
    float4 acc[12];
    #pragma unroll
    for (int i = 0; i < 12; ++i) acc[i] = make_float4(0.f, 0.f, 0.f, 0.f);

    const float4* Wl4 = (const float4*)Wl0;   // [IC][HC/4]
    const float4* Wr4 = (const float4*)Wr0;

    #pragma unroll 2
    for (int k = 0; k < IC; ++k) {
        float4 w = Wl4[k * (HC / 4) + c4];
        const float* row = &in_s[k][ng * 12];
        float4 a0 = *(const float4*)(row);
        float4 a1 = *(const float4*)(row + 4);
        float4 a2 = *(const float4*)(row + 8);
        fma4(acc[0], a0.x, w); fma4(acc[1], a0.y, w); fma4(acc[2], a0.z, w); fma4(acc[3], a0.w, w);
        fma4(acc[4], a1.x, w); fma4(acc[5], a1.y, w); fma4(acc[6], a1.z, w); fma4(acc[7], a1.w, w);
        fma4(acc[8], a2.x, w); fma4(acc[9], a2.y, w); fma4(acc[10], a2.z, w); fma4(acc[11], a2.w, w);
    }
    #pragma unroll 2
    for (int k = 0; k < IC; ++k) {
        float4 w = Wr4[k * (HC / 4) + c4];
        const float* row = &in_s[IC + k][ng * 12];
        float4 a0 = *(const float4*)(row);
        float4 a1 = *(const float4*)(row + 4);
        float4 a2 = *(const float4*)(row + 8);
        fma4(acc[0], a0.x, w); fma4(acc[1], a0.y, w); fma4(acc[2], a0.z, w); fma4(acc[3], a0.w, w);
        fma4(acc[4], a1.x, w); fma4(acc[5], a1.y, w); fma4(acc[6], a1.z, w); fma4(acc[7], a1.w, w);
        fma4(acc[8], a2.x, w); fma4(acc[9], a2.y, w); fma4(acc[10], a2.z, w); fma4(acc[11], a2.w, w);
    }

    // epilogue: bias + relu, then project to 3 outputs (l and r), reduce across the wave
    float4 b4 = ((const float4*)bl0)[c4];
    int c0 = c4 * 4;
    float wl1[4][3], wr1[4][3];
    #pragma unroll
    for (int c = 0; c < 4; ++c)
        #pragma unroll
        for (int j = 0; j < 3; ++j) {
            wl1[c][j] = Wl1[(c0 + c) * 3 + j];
            wr1[c][j] = Wr1[(c0 + c) * 3 + j];
        }

    #pragma unroll
    for (int i = 0; i < 12; ++i) {
        int node = nbase + ng * 12 + i;
        float4 h4;
        h4.x = fmaxf(acc[i].x + b4.x, 0.0f);
        h4.y = fmaxf(acc[i].y + b4.y, 0.0f);
        h4.z = fmaxf(acc[i].z + b4.z, 0.0f);
        h4.w = fmaxf(acc[i].w + b4.w, 0.0f);
        float pl[3], pr[3];
        #pragma unroll
        for (int j = 0; j < 3; ++j) {
            pl[j] = h4.x * wl1[0][j] + h4.y * wl1[1][j] + h4.z * wl1[2][j] + h4.w * wl1[3][j];
            pr[j] = h4.x * wr1[0][j] + h4.y * wr1[1][j] + h4.z * wr1[2][j] + h4.w * wr1[3][j];
        }
        #pragma unroll
        for (int off = 32; off > 0; off >>= 1) {
            #pragma unroll
            for (int j = 0; j < 3; ++j) {
                pl[j] += __shfl_xor(pl[j], off);
                pr[j] += __shfl_xor(pr[j], off);
            }
        }
        if ((t & 63) == 0 && node < NN) {
            g[node * 3 + 0] = pl[0]; g[node * 3 + 1] = pl[1]; g[node * 3 + 2] = pl[2];
            r[node * 3 + 0] = pr[0]; r[node * 3 + 1] = pr[1]; r[node * 3 + 2] = pr[2];
        }
    }
}

// ---------------- kernel 6: s1[dst] += g[src] (1.9M atomics on L2-resident 600KB) ----------------
__global__ __launch_bounds__(256) void k_scatter1(const int* __restrict__ ei,
                                                  const float* __restrict__ g,
                                                  float* __restrict__ s1) {
    int e = blockIdx.x * blockDim.x + threadIdx.x;
    if (e >= NE) return;
    int src = ei[e];
    int dst = ei[NE + e];
    unsafeAtomicAdd(&s1[dst * 3 + 0], g[src * 3 + 0]);
    unsafeAtomicAdd(&s1[dst * 3 + 1], g[src * 3 + 1]);
    unsafeAtomicAdd(&s1[dst * 3 + 2], g[src * 3 + 2]);
}

// ---------------- kernel 7: out = s1/deg + bl1 + r ----------------
__global__ __launch_bounds__(256) void k_final(const float* __restrict__ s1,
                                               const int* __restrict__ degi,
                                               const float* __restrict__ r,
                                               const float* __restrict__ bl1,
                                               float* __restrict__ out) {
    int i = blockIdx.x * blockDim.x + threadIdx.x;
    if (i >= NN * OC) return;
    int n = i / OC;
    int j = i - n * OC;
    float d = fmaxf((float)degi[n], 1.0f);
    out[i] = s1[i] / d + bl1[j] + r[i];
}

extern "C" void kernel_launch(void* const* d_in, const int* in_sizes, int n_in,
                              void* d_out, int out_size, void* d_ws, size_t ws_size,
                              hipStream_t stream) {
    const float* x   = (const float*)d_in[0];
    const int*   ei  = (const int*)d_in[1];
    const float* Wl0 = (const float*)d_in[2];
    const float* bl0 = (const float*)d_in[3];
    const float* Wr0 = (const float*)d_in[4];
    const float* Wl1 = (const float*)d_in[5];
    const float* bl1 = (const float*)d_in[6];
    const float* Wr1 = (const float*)d_in[7];
    float* out = (float*)d_out;

    char* ws = (char*)d_ws;
    int*   degi     = (int*)(ws);                        //    200,064 (NN, pad)
    float* s1       = (float*)(ws + 200064);             //    600,064 (NN*3, pad)
    int*   pos      = (int*)(ws + 800128);               //  2,560,000 (NE)
    int*   rowstart = (int*)(ws + 3360128);              //    200,064 (NN+1, pad)
    int*   csr      = (int*)(ws + 3560192);              //  2,560,000 (NE)
    float* agg0     = (float*)(ws + 6120192);            // 25,600,000 (NN*IC)
    float* g        = (float*)(ws + 31720192);           //    600,064
    float* r        = (float*)(ws + 32320256);           //    600,064  -> ~32.9 MB

    hipMemsetAsync(ws, 0, 800128, stream);               // degi + s1

    k_deg     <<<(NE + 255) / 256, 256, 0, stream>>>(ei, degi, pos);
    k_scan    <<<1, 1024, 0, stream>>>(degi, rowstart);
    k_fill    <<<(NE + 255) / 256, 256, 0, stream>>>(ei, rowstart, pos, csr);
    k_agg     <<<(NN * 64 + 255) / 256, 256, 0, stream>>>(x, rowstart, csr, agg0);
    k_gemm0f  <<<(NN + NT0 - 1) / NT0, 256, 0, stream>>>(x, agg0, Wl0, bl0, Wr0, Wl1, Wr1, g, r);
    k_scatter1<<<(NE + 255) / 256, 256, 0, stream>>>(ei, g, s1);
    k_final   <<<(NN * OC + 255) / 256, 256, 0, stream>>>(s1, degi, r, bl1, out);
}

// Round 4
// 338.539 us; speedup vs baseline: 4.0395x; 1.2378x over previous
//
#include <hip/hip_runtime.h>

#define NN 50000
#define NNP 50048   // Ab rows padded to multiple of 64
#define NE 640000
#define IC 128
#define HC 256
#define OC 3

typedef __attribute__((ext_vector_type(8))) short short8;
typedef __attribute__((ext_vector_type(4))) float f32x4;

__device__ __forceinline__ unsigned short f2bf(float f) {   // fp32 -> bf16 RNE
    unsigned int u = __float_as_uint(f);
    unsigned int r = u + 0x7FFFu + ((u >> 16) & 1u);
    return (unsigned short)(r >> 16);
}

// ---------------- CSR build ----------------
__global__ __launch_bounds__(256) void k_deg(const int* __restrict__ ei,
                                             int* __restrict__ degi,
                                             int* __restrict__ pos) {
    int e = blockIdx.x * blockDim.x + threadIdx.x;
    if (e >= NE) return;
    int dst = ei[NE + e];
    pos[e] = atomicAdd(&degi[dst], 1);
}

__global__ __launch_bounds__(1024) void k_scan(const int* __restrict__ degi,
                                               int* __restrict__ rowstart) {
    __shared__ int sums[1024];
    int t = threadIdx.x;
    const int CH = (NN + 1023) / 1024;
    int base = t * CH;
    int s = 0;
    for (int i = 0; i < CH; ++i) {
        int idx = base + i;
        if (idx < NN) s += degi[idx];
    }
    sums[t] = s;
    __syncthreads();
    for (int off = 1; off < 1024; off <<= 1) {
        int v = (t >= off) ? sums[t - off] : 0;
        __syncthreads();
        sums[t] += v;
        __syncthreads();
    }
    int excl = (t == 0) ? 0 : sums[t - 1];
    for (int i = 0; i < CH; ++i) {
        int idx = base + i;
        if (idx < NN) {
            rowstart[idx] = excl;
            excl += degi[idx];
        }
    }
    if (t == 1023) rowstart[NN] = NE;
}

__global__ __launch_bounds__(256) void k_fill(const int* __restrict__ ei,
                                              const int* __restrict__ rowstart,
                                              const int* __restrict__ pos,
                                              int* __restrict__ csr) {
    int e = blockIdx.x * blockDim.x + threadIdx.x;
    if (e >= NE) return;
    int src = ei[e];
    int dst = ei[NE + e];
    csr[rowstart[dst] + pos[e]] = src;
}

// ---------------- x -> bf16 into right half of Ab ----------------
// Ab: ushort[NNP][256]; cols 0..127 = mean (by k_agg), cols 128..255 = x
__global__ __launch_bounds__(256) void k_tobf16(const float* __restrict__ x,
                                                unsigned short* __restrict__ Ab) {
    int i = blockIdx.x * 256 + threadIdx.x;       // over NN*IC/4
    if (i >= NN * IC / 4) return;
    int n = i >> 5;               // 32 float4 per 128-ch row
    int c = (i & 31) * 4;
    float4 v = ((const float4*)x)[i];
    ushort4 o;
    o.x = f2bf(v.x); o.y = f2bf(v.y); o.z = f2bf(v.z); o.w = f2bf(v.w);
    *(ushort4*)&Ab[(size_t)n * 256 + 128 + c] = o;
}

// ---------------- pack [Wl0;Wr0] (256K x 256N) into MFMA B-fragment order ----------------
// Bp[kt(8)][nt(16)][lane(64)][e(8)] bf16, with B[k][n]: k = kt*32 + (lane>>4)*8 + e, n = nt*16 + (lane&15)
__global__ __launch_bounds__(256) void k_wpack(const float* __restrict__ Wl0,
                                               const float* __restrict__ Wr0,
                                               unsigned short* __restrict__ Bp) {
    int t = blockIdx.x * 256 + threadIdx.x;       // 8*16*64 = 8192 threads
    if (t >= 8 * 16 * 64) return;
    int l = t & 63;
    int nt = (t >> 6) & 15;
    int kt = t >> 10;
    int n = nt * 16 + (l & 15);
    int kbase = kt * 32 + (l >> 4) * 8;
    unsigned short o[8];
    #pragma unroll
    for (int e = 0; e < 8; ++e) {
        int k = kbase + e;
        float w = (k < IC) ? Wl0[k * HC + n] : Wr0[(k - IC) * HC + n];
        o[e] = f2bf(w);
    }
    #pragma unroll
    for (int e = 0; e < 8; ++e) Bp[(size_t)t * 8 + e] = o[e];
}

// ---------------- gather-mean (bf16 in, fp32 accum, bf16 out) ----------------
__global__ __launch_bounds__(256) void k_agg(const int* __restrict__ rowstart,
                                             const int* __restrict__ csr,
                                             unsigned short* __restrict__ Ab) {
    int wid = (blockIdx.x * blockDim.x + threadIdx.x) >> 6;
    int lane = threadIdx.x & 63;
    if (wid >= NN) return;
    int beg = rowstart[wid], end = rowstart[wid + 1];
    const unsigned int* base = (const unsigned int*)Ab;   // 128 uints per row
    float ax = 0.0f, ay = 0.0f;
    for (int j = beg; j < end; ++j) {
        int src = csr[j];
        unsigned int v = base[(size_t)src * 128 + 64 + lane];  // x half
        ax += __uint_as_float(v << 16);
        ay += __uint_as_float(v & 0xffff0000u);
    }
    float inv = 1.0f / fmaxf((float)(end - beg), 1.0f);
    ax *= inv; ay *= inv;
    unsigned int o = ((unsigned int)f2bf(ay) << 16) | (unsigned int)f2bf(ax);
    ((unsigned int*)Ab)[(size_t)wid * 128 + lane] = o;
}

// ---------------- MFMA GEMM + fused epilogue ----------------
// H = relu(Ab @ [Wl0;Wr0] + bl0); g = H@Wl1; r = H@Wr1
// block: 256 thr = 4 waves, 64 nodes. Wave: 16 nodes x 256 cols, K=256 (8 kt steps).
__global__ __launch_bounds__(256) void k_gemm(const unsigned short* __restrict__ Ab,
                                              const unsigned short* __restrict__ Bp,
                                              const float* __restrict__ bl0,
                                              const float* __restrict__ Wl1,
                                              const float* __restrict__ Wr1,
                                              float* __restrict__ g,
                                              float* __restrict__ r) {
    __shared__ float4 Bs[2048];          // 32 KB: one K-quarter of packed B
    __shared__ float wl1s[HC][3];
    __shared__ float wr1s[HC][3];
    __shared__ float bls[HC];

    int t = threadIdx.x;
    for (int i = t; i < HC * 3; i += 256) {
        wl1s[i / 3][i % 3] = Wl1[i];
        wr1s[i / 3][i % 3] = Wr1[i];
    }
    for (int i = t; i < HC; i += 256) bls[i] = bl0[i];

    int w = t >> 6, l = t & 63;
    int n0 = blockIdx.x * 64 + w * 16;

    f32x4 acc[16];
    #pragma unroll
    for (int i = 0; i < 16; ++i) acc[i] = (f32x4){0.f, 0.f, 0.f, 0.f};

    // A-frag: lane l supplies A[n0 + (l&15)][kt*32 + (l>>4)*8 + e]
    const short8* A8 = (const short8*)Ab + ((size_t)(n0 + (l & 15)) * 32 + (l >> 4));

    for (int q = 0; q < 4; ++q) {
        __syncthreads();
        const float4* gsrc = (const float4*)(Bp + (size_t)q * 16384);  // 32KB quarter
        #pragma unroll
        for (int i = 0; i < 8; ++i)
            Bs[i * 256 + t] = gsrc[i * 256 + t];
        __syncthreads();
        #pragma unroll
        for (int j = 0; j < 2; ++j) {
            int kt = q * 2 + j;
            short8 af = A8[kt * 4];
            const short8* B8 = (const short8*)Bs + (j * 1024 + l);
            #pragma unroll
            for (int nt = 0; nt < 16; ++nt) {
                short8 bf = B8[nt * 64];
                acc[nt] = __builtin_amdgcn_mfma_f32_16x16x32_bf16(af, bf, acc[nt], 0, 0, 0);
            }
        }
    }

    // epilogue: D lane l reg e = H[row=(l>>4)*4+e][col=nt*16+(l&15)]
    float pl[4][3] = {{0.f}}, pr[4][3] = {{0.f}};
    #pragma unroll
    for (int nt = 0; nt < 16; ++nt) {
        int col = nt * 16 + (l & 15);
        float b = bls[col];
        #pragma unroll
        for (int e = 0; e < 4; ++e) {
            float h = fmaxf(acc[nt][e] + b, 0.0f);
            #pragma unroll
            for (int j = 0; j < 3; ++j) {
                pl[e][j] = fmaf(h, wl1s[col][j], pl[e][j]);
                pr[e][j] = fmaf(h, wr1s[col][j], pr[e][j]);
            }
        }
    }
    #pragma unroll
    for (int m = 1; m <= 8; m <<= 1) {
        #pragma unroll
        for (int e = 0; e < 4; ++e)
            #pragma unroll
            for (int j = 0; j < 3; ++j) {
                pl[e][j] += __shfl_xor(pl[e][j], m);
                pr[e][j] += __shfl_xor(pr[e][j], m);
            }
    }
    if ((l & 15) == 0) {
        #pragma unroll
        for (int e = 0; e < 4; ++e) {
            int node = n0 + (l >> 4) * 4 + e;
            if (node < NN) {
                #pragma unroll
                for (int j = 0; j < 3; ++j) {
                    g[node * 3 + j] = pl[e][j];
                    r[node * 3 + j] = pr[e][j];
                }
            }
        }
    }
}

// ---------------- scatter layer-1 messages ----------------
__global__ __launch_bounds__(256) void k_scatter1(const int* __restrict__ ei,
                                                  const float* __restrict__ g,
                                                  float* __restrict__ s1) {
    int e = blockIdx.x * blockDim.x + threadIdx.x;
    if (e >= NE) return;
    int src = ei[e];
    int dst = ei[NE + e];
    unsafeAtomicAdd(&s1[dst * 3 + 0], g[src * 3 + 0]);
    unsafeAtomicAdd(&s1[dst * 3 + 1], g[src * 3 + 1]);
    unsafeAtomicAdd(&s1[dst * 3 + 2], g[src * 3 + 2]);
}

__global__ __launch_bounds__(256) void k_final(const float* __restrict__ s1,
                                               const int* __restrict__ degi,
                                               const float* __restrict__ r,
                                               const float* __restrict__ bl1,
                                               float* __restrict__ out) {
    int i = blockIdx.x * blockDim.x + threadIdx.x;
    if (i >= NN * OC) return;
    int n = i / OC;
    int j = i - n * OC;
    float d = fmaxf((float)degi[n], 1.0f);
    out[i] = s1[i] / d + bl1[j] + r[i];
}

extern "C" void kernel_launch(void* const* d_in, const int* in_sizes, int n_in,
                              void* d_out, int out_size, void* d_ws, size_t ws_size,
                              hipStream_t stream) {
    const float* x   = (const float*)d_in[0];
    const int*   ei  = (const int*)d_in[1];
    const float* Wl0 = (const float*)d_in[2];
    const float* bl0 = (const float*)d_in[3];
    const float* Wr0 = (const float*)d_in[4];
    const float* Wl1 = (const float*)d_in[5];
    const float* bl1 = (const float*)d_in[6];
    const float* Wr1 = (const float*)d_in[7];
    float* out = (float*)d_out;

    char* ws = (char*)d_ws;
    int*            degi     = (int*)(ws);                   //    200,064
    float*          s1       = (float*)(ws + 200064);        //    600,064
    int*            pos      = (int*)(ws + 800128);          //  2,560,000
    int*            rowstart = (int*)(ws + 3360128);         //    200,064
    int*            csr      = (int*)(ws + 3560192);         //  2,560,000
    unsigned short* Ab       = (unsigned short*)(ws + 6120192);   // 25,624,576 (NNP*256*2)
    unsigned short* Bp       = (unsigned short*)(ws + 31744768);  //    131,072
    float*          g        = (float*)(ws + 31875840);      //    600,064
    float*          r        = (float*)(ws + 32475904);      //    600,064  -> ~33.1 MB

    hipMemsetAsync(ws, 0, 800128, stream);   // degi + s1

    k_tobf16  <<<NN * IC / 4 / 256, 256, 0, stream>>>(x, Ab);
    k_wpack   <<<32, 256, 0, stream>>>(Wl0, Wr0, Bp);
    k_deg     <<<(NE + 255) / 256, 256, 0, stream>>>(ei, degi, pos);
    k_scan    <<<1, 1024, 0, stream>>>(degi, rowstart);
    k_fill    <<<(NE + 255) / 256, 256, 0, stream>>>(ei, rowstart, pos, csr);
    k_agg     <<<(NN * 64 + 255) / 256, 256, 0, stream>>>(rowstart, csr, Ab);
    k_gemm    <<<(NN + 63) / 64, 256, 0, stream>>>(Ab, Bp, bl0, Wl1, Wr1, g, r);
    k_scatter1<<<(NE + 255) / 256, 256, 0, stream>>>(ei, g, s1);
    k_final   <<<(NN * OC + 255) / 256, 256, 0, stream>>>(s1, degi, r, bl1, out);
}

// Round 5
// 241.110 us; speedup vs baseline: 5.6718x; 1.4041x over previous
//
#include <hip/hip_runtime.h>

#define NN 50000
#define NNP 50048   // Ab rows padded to multiple of 64
#define NE 640000
#define IC 128
#define HC 256
#define OC 3

typedef __attribute__((ext_vector_type(8))) short short8;
typedef __attribute__((ext_vector_type(4))) float f32x4;

__device__ __forceinline__ unsigned short f2bf(float f) {   // fp32 -> bf16 RNE
    unsigned int u = __float_as_uint(f);
    unsigned int r = u + 0x7FFFu + ((u >> 16) & 1u);
    return (unsigned short)(r >> 16);
}

// ---------------- CSR build ----------------
__global__ __launch_bounds__(256) void k_deg(const int* __restrict__ ei,
                                             int* __restrict__ degi,
                                             int* __restrict__ pos) {
    int e = blockIdx.x * blockDim.x + threadIdx.x;
    if (e >= NE) return;
    int dst = ei[NE + e];
    pos[e] = atomicAdd(&degi[dst], 1);
}

__global__ __launch_bounds__(1024) void k_scan(const int* __restrict__ degi,
                                               int* __restrict__ rowstart) {
    __shared__ int sums[1024];
    int t = threadIdx.x;
    const int CH = (NN + 1023) / 1024;
    int base = t * CH;
    int s = 0;
    for (int i = 0; i < CH; ++i) {
        int idx = base + i;
        if (idx < NN) s += degi[idx];
    }
    sums[t] = s;
    __syncthreads();
    for (int off = 1; off < 1024; off <<= 1) {
        int v = (t >= off) ? sums[t - off] : 0;
        __syncthreads();
        sums[t] += v;
        __syncthreads();
    }
    int excl = (t == 0) ? 0 : sums[t - 1];
    for (int i = 0; i < CH; ++i) {
        int idx = base + i;
        if (idx < NN) {
            rowstart[idx] = excl;
            excl += degi[idx];
        }
    }
    if (t == 1023) rowstart[NN] = NE;
}

__global__ __launch_bounds__(256) void k_fill(const int* __restrict__ ei,
                                              const int* __restrict__ rowstart,
                                              const int* __restrict__ pos,
                                              int* __restrict__ csr) {
    int e = blockIdx.x * blockDim.x + threadIdx.x;
    if (e >= NE) return;
    int src = ei[e];
    int dst = ei[NE + e];
    csr[rowstart[dst] + pos[e]] = src;
}

// ---------------- x -> bf16 into right half of Ab ----------------
// Ab: ushort[NNP][256]; cols 0..127 = mean (by k_agg), cols 128..255 = x
__global__ __launch_bounds__(256) void k_tobf16(const float* __restrict__ x,
                                                unsigned short* __restrict__ Ab) {
    int i = blockIdx.x * 256 + threadIdx.x;       // over NN*IC/4
    if (i >= NN * IC / 4) return;
    int n = i >> 5;               // 32 float4 per 128-ch row
    int c = (i & 31) * 4;
    float4 v = ((const float4*)x)[i];
    ushort4 o;
    o.x = f2bf(v.x); o.y = f2bf(v.y); o.z = f2bf(v.z); o.w = f2bf(v.w);
    *(ushort4*)&Ab[(size_t)n * 256 + 128 + c] = o;
}

// ---------------- pack [Wl0;Wr0] (256K x 256N) into MFMA B-fragment order ----------------
// Bp[kt(8)][nt(16)][lane(64)][e(8)] bf16, with B[k][n]: k = kt*32 + (lane>>4)*8 + e, n = nt*16 + (lane&15)
__global__ __launch_bounds__(256) void k_wpack(const float* __restrict__ Wl0,
                                               const float* __restrict__ Wr0,
                                               unsigned short* __restrict__ Bp) {
    int t = blockIdx.x * 256 + threadIdx.x;       // 8*16*64 = 8192 threads
    if (t >= 8 * 16 * 64) return;
    int l = t & 63;
    int nt = (t >> 6) & 15;
    int kt = t >> 10;
    int n = nt * 16 + (l & 15);
    int kbase = kt * 32 + (l >> 4) * 8;
    unsigned short o[8];
    #pragma unroll
    for (int e = 0; e < 8; ++e) {
        int k = kbase + e;
        float w = (k < IC) ? Wl0[k * HC + n] : Wr0[(k - IC) * HC + n];
        o[e] = f2bf(w);
    }
    #pragma unroll
    for (int e = 0; e < 8; ++e) Bp[(size_t)t * 8 + e] = o[e];
}

// ---------------- gather-mean (bf16 in, fp32 accum, bf16 out) ----------------
__global__ __launch_bounds__(256) void k_agg(const int* __restrict__ rowstart,
                                             const int* __restrict__ csr,
                                             unsigned short* __restrict__ Ab) {
    int wid = (blockIdx.x * blockDim.x + threadIdx.x) >> 6;
    int lane = threadIdx.x & 63;
    if (wid >= NN) return;
    int beg = rowstart[wid], end = rowstart[wid + 1];
    const unsigned int* base = (const unsigned int*)Ab;   // 128 uints per row
    float ax = 0.0f, ay = 0.0f;
    for (int j = beg; j < end; ++j) {
        int src = csr[j];
        unsigned int v = base[(size_t)src * 128 + 64 + lane];  // x half
        ax += __uint_as_float(v << 16);
        ay += __uint_as_float(v & 0xffff0000u);
    }
    float inv = 1.0f / fmaxf((float)(end - beg), 1.0f);
    ax *= inv; ay *= inv;
    unsigned int o = ((unsigned int)f2bf(ay) << 16) | (unsigned int)f2bf(ax);
    ((unsigned int*)Ab)[(size_t)wid * 128 + lane] = o;
}

// ---------------- MFMA GEMM + fused epilogue ----------------
// H = relu(Ab @ [Wl0;Wr0] + bl0); g = H@Wl1; r = H@Wr1
__global__ __launch_bounds__(256) void k_gemm(const unsigned short* __restrict__ Ab,
                                              const unsigned short* __restrict__ Bp,
                                              const float* __restrict__ bl0,
                                              const float* __restrict__ Wl1,
                                              const float* __restrict__ Wr1,
                                              float* __restrict__ g,
                                              float* __restrict__ r) {
    __shared__ float4 Bs[2048];          // 32 KB: one K-quarter of packed B
    __shared__ float wl1s[HC][3];
    __shared__ float wr1s[HC][3];
    __shared__ float bls[HC];

    int t = threadIdx.x;
    for (int i = t; i < HC * 3; i += 256) {
        wl1s[i / 3][i % 3] = Wl1[i];
        wr1s[i / 3][i % 3] = Wr1[i];
    }
    for (int i = t; i < HC; i += 256) bls[i] = bl0[i];

    int w = t >> 6, l = t & 63;
    int n0 = blockIdx.x * 64 + w * 16;

    f32x4 acc[16];
    #pragma unroll
    for (int i = 0; i < 16; ++i) acc[i] = (f32x4){0.f, 0.f, 0.f, 0.f};

    // A-frag: lane l supplies A[n0 + (l&15)][kt*32 + (l>>4)*8 + e]
    const short8* A8 = (const short8*)Ab + ((size_t)(n0 + (l & 15)) * 32 + (l >> 4));

    for (int q = 0; q < 4; ++q) {
        __syncthreads();
        const float4* gsrc = (const float4*)(Bp + (size_t)q * 16384);  // 32KB quarter
        #pragma unroll
        for (int i = 0; i < 8; ++i)
            Bs[i * 256 + t] = gsrc[i * 256 + t];
        __syncthreads();
        #pragma unroll
        for (int j = 0; j < 2; ++j) {
            int kt = q * 2 + j;
            short8 af = A8[kt * 4];
            const short8* B8 = (const short8*)Bs + (j * 1024 + l);
            #pragma unroll
            for (int nt = 0; nt < 16; ++nt) {
                short8 bf = B8[nt * 64];
                acc[nt] = __builtin_amdgcn_mfma_f32_16x16x32_bf16(af, bf, acc[nt], 0, 0, 0);
            }
        }
    }

    // epilogue: D lane l reg e = H[row=(l>>4)*4+e][col=nt*16+(l&15)]
    float pl[4][3] = {{0.f}}, pr[4][3] = {{0.f}};
    #pragma unroll
    for (int nt = 0; nt < 16; ++nt) {
        int col = nt * 16 + (l & 15);
        float b = bls[col];
        #pragma unroll
        for (int e = 0; e < 4; ++e) {
            float h = fmaxf(acc[nt][e] + b, 0.0f);
            #pragma unroll
            for (int j = 0; j < 3; ++j) {
                pl[e][j] = fmaf(h, wl1s[col][j], pl[e][j]);
                pr[e][j] = fmaf(h, wr1s[col][j], pr[e][j]);
            }
        }
    }
    #pragma unroll
    for (int m = 1; m <= 8; m <<= 1) {
        #pragma unroll
        for (int e = 0; e < 4; ++e)
            #pragma unroll
            for (int j = 0; j < 3; ++j) {
                pl[e][j] += __shfl_xor(pl[e][j], m);
                pr[e][j] += __shfl_xor(pr[e][j], m);
            }
    }
    if ((l & 15) == 0) {
        #pragma unroll
        for (int e = 0; e < 4; ++e) {
            int node = n0 + (l >> 4) * 4 + e;
            if (node < NN) {
                #pragma unroll
                for (int j = 0; j < 3; ++j) {
                    g[node * 3 + j] = pl[e][j];
                    r[node * 3 + j] = pr[e][j];
                }
            }
        }
    }
}

// ---------------- fused layer-1 aggregation by GATHER + final output ----------------
// out[n] = (sum_{src in csr row n} g[src]) / deg + bl1 + r[n]
// 8 lanes per node: edge-parallel partials, shuffle-reduce within the 8-lane group.
__global__ __launch_bounds__(256) void k_out(const int* __restrict__ rowstart,
                                             const int* __restrict__ csr,
                                             const float* __restrict__ g,
                                             const float* __restrict__ r,
                                             const float* __restrict__ bl1,
                                             float* __restrict__ out) {
    int tid = blockIdx.x * 256 + threadIdx.x;
    int n = tid >> 3;
    int sl = tid & 7;
    if (n >= NN) return;
    int beg = rowstart[n], end = rowstart[n + 1];
    float s0 = 0.f, s1 = 0.f, s2 = 0.f;
    for (int j = beg + sl; j < end; j += 8) {
        int src = csr[j];
        s0 += g[src * 3 + 0];
        s1 += g[src * 3 + 1];
        s2 += g[src * 3 + 2];
    }
    #pragma unroll
    for (int m = 1; m < 8; m <<= 1) {
        s0 += __shfl_xor(s0, m);
        s1 += __shfl_xor(s1, m);
        s2 += __shfl_xor(s2, m);
    }
    if (sl == 0) {
        float inv = 1.0f / fmaxf((float)(end - beg), 1.0f);
        out[n * 3 + 0] = s0 * inv + bl1[0] + r[n * 3 + 0];
        out[n * 3 + 1] = s1 * inv + bl1[1] + r[n * 3 + 1];
        out[n * 3 + 2] = s2 * inv + bl1[2] + r[n * 3 + 2];
    }
}

extern "C" void kernel_launch(void* const* d_in, const int* in_sizes, int n_in,
                              void* d_out, int out_size, void* d_ws, size_t ws_size,
                              hipStream_t stream) {
    const float* x   = (const float*)d_in[0];
    const int*   ei  = (const int*)d_in[1];
    const float* Wl0 = (const float*)d_in[2];
    const float* bl0 = (const float*)d_in[3];
    const float* Wr0 = (const float*)d_in[4];
    const float* Wl1 = (const float*)d_in[5];
    const float* bl1 = (const float*)d_in[6];
    const float* Wr1 = (const float*)d_in[7];
    float* out = (float*)d_out;

    char* ws = (char*)d_ws;
    int*            degi     = (int*)(ws);                        //    200,064
    int*            pos      = (int*)(ws + 200064);               //  2,560,000
    int*            rowstart = (int*)(ws + 2760064);              //    200,064
    int*            csr      = (int*)(ws + 2960128);              //  2,560,000
    unsigned short* Ab       = (unsigned short*)(ws + 5520128);   // 25,624,576 (NNP*256*2)
    unsigned short* Bp       = (unsigned short*)(ws + 31144704);  //    131,072
    float*          g        = (float*)(ws + 31275776);           //    600,064
    float*          r        = (float*)(ws + 31875840);           //    600,064  -> ~32.5 MB

    hipMemsetAsync(ws, 0, 200064, stream);   // degi only

    k_tobf16  <<<NN * IC / 4 / 256, 256, 0, stream>>>(x, Ab);
    k_wpack   <<<32, 256, 0, stream>>>(Wl0, Wr0, Bp);
    k_deg     <<<(NE + 255) / 256, 256, 0, stream>>>(ei, degi, pos);
    k_scan    <<<1, 1024, 0, stream>>>(degi, rowstart);
    k_fill    <<<(NE + 255) / 256, 256, 0, stream>>>(ei, rowstart, pos, csr);
    k_agg     <<<(NN * 64 + 255) / 256, 256, 0, stream>>>(rowstart, csr, Ab);
    k_gemm    <<<(NN + 63) / 64, 256, 0, stream>>>(Ab, Bp, bl0, Wl1, Wr1, g, r);
    k_out     <<<(NN * 8 + 255) / 256, 256, 0, stream>>>(rowstart, csr, g, r, bl1, out);
}

// Round 6
// 132.909 us; speedup vs baseline: 10.2893x; 1.8141x over previous
//
#include <hip/hip_runtime.h>

#define NN 50000
#define NNP 50048   // Ab rows padded to multiple of 64
#define NE 640000
#define IC 128
#define HC 256
#define OC 3

typedef __attribute__((ext_vector_type(8))) short short8;
typedef __attribute__((ext_vector_type(4))) float f32x4;

__device__ __forceinline__ unsigned short f2bf(float f) {   // fp32 -> bf16 RNE
    unsigned int u = __float_as_uint(f);
    unsigned int r = u + 0x7FFFu + ((u >> 16) & 1u);
    return (unsigned short)(r >> 16);
}
__device__ __forceinline__ float bflo(unsigned int v) { return __uint_as_float(v << 16); }
__device__ __forceinline__ float bfhi(unsigned int v) { return __uint_as_float(v & 0xffff0000u); }

// ---------------- CSR build ----------------
__global__ __launch_bounds__(256) void k_deg(const int* __restrict__ ei,
                                             int* __restrict__ degi,
                                             int* __restrict__ pos) {
    int e = blockIdx.x * blockDim.x + threadIdx.x;
    if (e >= NE) return;
    int dst = ei[NE + e];
    pos[e] = atomicAdd(&degi[dst], 1);
}

// ticket allocator replaces the prefix scan: regions are disjoint+contiguous,
// monotone order is never needed downstream (beg = rowstart[n], len = degi[n]).
__global__ __launch_bounds__(256) void k_ticket(const int* __restrict__ degi,
                                                int* __restrict__ counter,
                                                int* __restrict__ rowstart) {
    int n = blockIdx.x * blockDim.x + threadIdx.x;
    if (n >= NN) return;
    rowstart[n] = atomicAdd(counter, degi[n]);
}

__global__ __launch_bounds__(256) void k_fill(const int* __restrict__ ei,
                                              const int* __restrict__ rowstart,
                                              const int* __restrict__ pos,
                                              int* __restrict__ csr) {
    int e = blockIdx.x * blockDim.x + threadIdx.x;
    if (e >= NE) return;
    int src = ei[e];
    int dst = ei[NE + e];
    csr[rowstart[dst] + pos[e]] = src;
}

// ---------------- x -> bf16 into right half of Ab ----------------
// Ab: ushort[NNP][256]; cols 0..127 = mean (by k_agg), cols 128..255 = x
__global__ __launch_bounds__(256) void k_tobf16(const float* __restrict__ x,
                                                unsigned short* __restrict__ Ab) {
    int i = blockIdx.x * 256 + threadIdx.x;       // over NN*IC/4
    if (i >= NN * IC / 4) return;
    int n = i >> 5;               // 32 float4 per 128-ch row
    int c = (i & 31) * 4;
    float4 v = ((const float4*)x)[i];
    ushort4 o;
    o.x = f2bf(v.x); o.y = f2bf(v.y); o.z = f2bf(v.z); o.w = f2bf(v.w);
    *(ushort4*)&Ab[(size_t)n * 256 + 128 + c] = o;
}

// ---------------- pack [Wl0;Wr0] (256K x 256N) into MFMA B-fragment order ----------------
__global__ __launch_bounds__(256) void k_wpack(const float* __restrict__ Wl0,
                                               const float* __restrict__ Wr0,
                                               unsigned short* __restrict__ Bp) {
    int t = blockIdx.x * 256 + threadIdx.x;       // 8*16*64 = 8192 threads
    if (t >= 8 * 16 * 64) return;
    int l = t & 63;
    int nt = (t >> 6) & 15;
    int kt = t >> 10;
    int n = nt * 16 + (l & 15);
    int kbase = kt * 32 + (l >> 4) * 8;
    unsigned short o[8];
    #pragma unroll
    for (int e = 0; e < 8; ++e) {
        int k = kbase + e;
        float w = (k < IC) ? Wl0[k * HC + n] : Wr0[(k - IC) * HC + n];
        o[e] = f2bf(w);
    }
    #pragma unroll
    for (int e = 0; e < 8; ++e) Bp[(size_t)t * 8 + e] = o[e];
}

// ---------------- gather-mean: 4 edge-subgroups x 16 lanes x uint4 ----------------
__global__ __launch_bounds__(256) void k_agg(const int* __restrict__ rowstart,
                                             const int* __restrict__ degi,
                                             const int* __restrict__ csr,
                                             unsigned short* __restrict__ Ab) {
    int wid = (blockIdx.x * blockDim.x + threadIdx.x) >> 6;
    int lane = threadIdx.x & 63;
    if (wid >= NN) return;
    int beg = rowstart[wid];
    int deg = degi[wid];
    int sg = lane >> 4;        // edge subgroup 0..3
    int s  = lane & 15;        // uint4 slot within row (x-half = slots 16..31)
    const uint4* base = (const uint4*)Ab;     // 32 uint4 per 512B row

    float a[8] = {0.f, 0.f, 0.f, 0.f, 0.f, 0.f, 0.f, 0.f};
    for (int j = beg + sg; j < beg + deg; j += 4) {
        int src = csr[j];
        uint4 v = base[(size_t)src * 32 + 16 + s];
        a[0] += bflo(v.x); a[1] += bfhi(v.x);
        a[2] += bflo(v.y); a[3] += bfhi(v.y);
        a[4] += bflo(v.z); a[5] += bfhi(v.z);
        a[6] += bflo(v.w); a[7] += bfhi(v.w);
    }
    #pragma unroll
    for (int m = 16; m <= 32; m <<= 1)
        #pragma unroll
        for (int i = 0; i < 8; ++i) a[i] += __shfl_xor(a[i], m);

    if (sg == 0) {
        float inv = 1.0f / fmaxf((float)deg, 1.0f);
        uint4 o;
        o.x = ((unsigned int)f2bf(a[1] * inv) << 16) | f2bf(a[0] * inv);
        o.y = ((unsigned int)f2bf(a[3] * inv) << 16) | f2bf(a[2] * inv);
        o.z = ((unsigned int)f2bf(a[5] * inv) << 16) | f2bf(a[4] * inv);
        o.w = ((unsigned int)f2bf(a[7] * inv) << 16) | f2bf(a[6] * inv);
        ((uint4*)Ab)[(size_t)wid * 32 + s] = o;
    }
}

// ---------------- MFMA GEMM + fused epilogue ----------------
// H = relu(Ab @ [Wl0;Wr0] + bl0); g = H@Wl1; r = H@Wr1
__global__ __launch_bounds__(256) void k_gemm(const unsigned short* __restrict__ Ab,
                                              const unsigned short* __restrict__ Bp,
                                              const float* __restrict__ bl0,
                                              const float* __restrict__ Wl1,
                                              const float* __restrict__ Wr1,
                                              float* __restrict__ g,
                                              float* __restrict__ r) {
    __shared__ float4 Bs[2048];          // 32 KB: one K-quarter of packed B
    __shared__ float wl1s[HC][3];
    __shared__ float wr1s[HC][3];
    __shared__ float bls[HC];

    int t = threadIdx.x;
    for (int i = t; i < HC * 3; i += 256) {
        wl1s[i / 3][i % 3] = Wl1[i];
        wr1s[i / 3][i % 3] = Wr1[i];
    }
    for (int i = t; i < HC; i += 256) bls[i] = bl0[i];

    int w = t >> 6, l = t & 63;
    int n0 = blockIdx.x * 64 + w * 16;

    f32x4 acc[16];
    #pragma unroll
    for (int i = 0; i < 16; ++i) acc[i] = (f32x4){0.f, 0.f, 0.f, 0.f};

    // A-frag: lane l supplies A[n0 + (l&15)][kt*32 + (l>>4)*8 + e]
    const short8* A8 = (const short8*)Ab + ((size_t)(n0 + (l & 15)) * 32 + (l >> 4));

    for (int q = 0; q < 4; ++q) {
        __syncthreads();
        const float4* gsrc = (const float4*)(Bp + (size_t)q * 16384);  // 32KB quarter
        #pragma unroll
        for (int i = 0; i < 8; ++i)
            Bs[i * 256 + t] = gsrc[i * 256 + t];
        __syncthreads();
        #pragma unroll
        for (int j = 0; j < 2; ++j) {
            int kt = q * 2 + j;
            short8 af = A8[kt * 4];
            const short8* B8 = (const short8*)Bs + (j * 1024 + l);
            #pragma unroll
            for (int nt = 0; nt < 16; ++nt) {
                short8 bf = B8[nt * 64];
                acc[nt] = __builtin_amdgcn_mfma_f32_16x16x32_bf16(af, bf, acc[nt], 0, 0, 0);
            }
        }
    }

    // epilogue: D lane l reg e = H[row=(l>>4)*4+e][col=nt*16+(l&15)]
    float pl[4][3] = {{0.f}}, pr[4][3] = {{0.f}};
    #pragma unroll
    for (int nt = 0; nt < 16; ++nt) {
        int col = nt * 16 + (l & 15);
        float b = bls[col];
        #pragma unroll
        for (int e = 0; e < 4; ++e) {
            float h = fmaxf(acc[nt][e] + b, 0.0f);
            #pragma unroll
            for (int j = 0; j < 3; ++j) {
                pl[e][j] = fmaf(h, wl1s[col][j], pl[e][j]);
                pr[e][j] = fmaf(h, wr1s[col][j], pr[e][j]);
            }
        }
    }
    #pragma unroll
    for (int m = 1; m <= 8; m <<= 1) {
        #pragma unroll
        for (int e = 0; e < 4; ++e)
            #pragma unroll
            for (int j = 0; j < 3; ++j) {
                pl[e][j] += __shfl_xor(pl[e][j], m);
                pr[e][j] += __shfl_xor(pr[e][j], m);
            }
    }
    if ((l & 15) == 0) {
        #pragma unroll
        for (int e = 0; e < 4; ++e) {
            int node = n0 + (l >> 4) * 4 + e;
            if (node < NN) {
                #pragma unroll
                for (int j = 0; j < 3; ++j) {
                    g[node * 3 + j] = pl[e][j];
                    r[node * 3 + j] = pr[e][j];
                }
            }
        }
    }
}

// ---------------- fused layer-1 aggregation by GATHER + final output ----------------
__global__ __launch_bounds__(256) void k_out(const int* __restrict__ rowstart,
                                             const int* __restrict__ degi,
                                             const int* __restrict__ csr,
                                             const float* __restrict__ g,
                                             const float* __restrict__ r,
                                             const float* __restrict__ bl1,
                                             float* __restrict__ out) {
    int tid = blockIdx.x * 256 + threadIdx.x;
    int n = tid >> 3;
    int sl = tid & 7;
    if (n >= NN) return;
    int beg = rowstart[n];
    int deg = degi[n];
    float s0 = 0.f, s1 = 0.f, s2 = 0.f;
    for (int j = beg + sl; j < beg + deg; j += 8) {
        int src = csr[j];
        s0 += g[src * 3 + 0];
        s1 += g[src * 3 + 1];
        s2 += g[src * 3 + 2];
    }
    #pragma unroll
    for (int m = 1; m < 8; m <<= 1) {
        s0 += __shfl_xor(s0, m);
        s1 += __shfl_xor(s1, m);
        s2 += __shfl_xor(s2, m);
    }
    if (sl == 0) {
        float inv = 1.0f / fmaxf((float)deg, 1.0f);
        out[n * 3 + 0] = s0 * inv + bl1[0] + r[n * 3 + 0];
        out[n * 3 + 1] = s1 * inv + bl1[1] + r[n * 3 + 1];
        out[n * 3 + 2] = s2 * inv + bl1[2] + r[n * 3 + 2];
    }
}

extern "C" void kernel_launch(void* const* d_in, const int* in_sizes, int n_in,
                              void* d_out, int out_size, void* d_ws, size_t ws_size,
                              hipStream_t stream) {
    const float* x   = (const float*)d_in[0];
    const int*   ei  = (const int*)d_in[1];
    const float* Wl0 = (const float*)d_in[2];
    const float* bl0 = (const float*)d_in[3];
    const float* Wr0 = (const float*)d_in[4];
    const float* Wl1 = (const float*)d_in[5];
    const float* bl1 = (const float*)d_in[6];
    const float* Wr1 = (const float*)d_in[7];
    float* out = (float*)d_out;

    char* ws = (char*)d_ws;
    int*            degi     = (int*)(ws);                        // 200,000 (NN)
    int*            counter  = (int*)(ws + 200000);               //       4 (+pad to 200,064)
    int*            pos      = (int*)(ws + 200064);               //  2,560,000
    int*            rowstart = (int*)(ws + 2760064);              //    200,064
    int*            csr      = (int*)(ws + 2960128);              //  2,560,000
    unsigned short* Ab       = (unsigned short*)(ws + 5520128);   // 25,624,576 (NNP*256*2)
    unsigned short* Bp       = (unsigned short*)(ws + 31144704);  //    131,072
    float*          g        = (float*)(ws + 31275776);           //    600,064
    float*          r        = (float*)(ws + 31875840);           //    600,064  -> ~32.5 MB

    hipMemsetAsync(ws, 0, 200064, stream);   // degi + counter

    k_tobf16  <<<NN * IC / 4 / 256, 256, 0, stream>>>(x, Ab);
    k_wpack   <<<32, 256, 0, stream>>>(Wl0, Wr0, Bp);
    k_deg     <<<(NE + 255) / 256, 256, 0, stream>>>(ei, degi, pos);
    k_ticket  <<<(NN + 255) / 256, 256, 0, stream>>>(degi, counter, rowstart);
    k_fill    <<<(NE + 255) / 256, 256, 0, stream>>>(ei, rowstart, pos, csr);
    k_agg     <<<(NN * 64 + 255) / 256, 256, 0, stream>>>(rowstart, degi, csr, Ab);
    k_gemm    <<<(NN + 63) / 64, 256, 0, stream>>>(Ab, Bp, bl0, Wl1, Wr1, g, r);
    k_out     <<<(NN * 8 + 255) / 256, 256, 0, stream>>>(rowstart, degi, csr, g, r, bl1, out);
}